// Round 1
// baseline (346.739 us; speedup 1.0000x reference)
//
#include <hip/hip_runtime.h>

// W4A8 per-group GEMM, MI355X (gfx950).
// out[m,n] = (sum_k x_i8[m,k] * (q4[n,k]*s2[g,n] + z[g,n])) * is[m] * s1[n] + b[n]
// Exact int8 MFMA path: dequant w_int8 = q*s2+z (fits [-105,105]) during LDS staging.

typedef int v4i __attribute__((ext_vector_type(4)));

#define MM 64
#define KK 4096
#define NN 14336
#define GG 32
#define BN 64
#define BK 64
#define NT (KK / BK)   // 64 k-tiles

__global__ __launch_bounds__(256) void w4a8_gemm_kernel(
    const int* __restrict__ x,            // [64][4096] int8 in int32
    const float* __restrict__ input_scales, // [64]
    const int* __restrict__ qweight,      // [14336][4096] uint4 in int32
    const int* __restrict__ s2_scales,    // [32][14336]
    const int* __restrict__ s2_zeros,     // [32][14336]
    const float* __restrict__ s1_scales,  // [14336]
    const float* __restrict__ bias,       // [14336]
    float* __restrict__ out)              // [64][14336] fp32
{
    // +1 dword row pad -> 17-dword stride: 64 lanes spread ~2 lanes/bank (free).
    __shared__ int x_lds[64 * 17];
    __shared__ int w_lds[64 * 17];
    __shared__ int s2_lds[GG * BN];
    __shared__ int z_lds[GG * BN];

    const int t  = threadIdx.x;
    const int n0 = blockIdx.x * BN;

    // Preload this block's s2/z panels (32 g x 64 n) into LDS once.
    for (int i = t; i < GG * BN; i += 256) {
        int g = i >> 6;
        int n = i & 63;
        s2_lds[i] = s2_scales[g * NN + n0 + n];
        z_lds[i]  = s2_zeros [g * NN + n0 + n];
    }
    __syncthreads();

    // Staging map: thread t covers rows r = (t>>4)+16j (j=0..3), dword-quad c4 = t&15.
    // 16 lanes x 16B = 256B contiguous per row chunk -> good coalescing.
    const int rbase = t >> 4;   // 0..15
    const int c4    = t & 15;   // 0..15

    v4i qv[4], xv[4];
    #pragma unroll
    for (int j = 0; j < 4; ++j) {
        int r = rbase + 16 * j;
        qv[j] = *(const v4i*)(qweight + (size_t)(n0 + r) * KK + c4 * 4);
        xv[j] = *(const v4i*)(x       + (size_t)r        * KK + c4 * 4);
    }

    const int lane = t & 63;
    const int wv   = t >> 6;      // wave id 0..3 -> n sub-tile
    const int arow = lane & 15;   // fragment row/col index
    const int kq   = lane >> 4;   // 0..3 k-quarter

    v4i acc[4];
    #pragma unroll
    for (int q = 0; q < 4; ++q) acc[q] = (v4i){0, 0, 0, 0};

    for (int it = 0; it < NT; ++it) {
        const int g = it >> 1;  // group id (128 k per group = 2 tiles)

        // ---- pack + dequant into LDS (consumes qv/xv) ----
        #pragma unroll
        for (int j = 0; j < 4; ++j) {
            int r = rbase + 16 * j;
            int s2v = s2_lds[g * 64 + r];
            int zv  = z_lds [g * 64 + r];
            v4i q4 = qv[j];
            int w0 = q4.x * s2v + zv;
            int w1 = q4.y * s2v + zv;
            int w2 = q4.z * s2v + zv;
            int w3 = q4.w * s2v + zv;
            unsigned pw = (unsigned)(w0 & 255)
                        | ((unsigned)(w1 & 255) << 8)
                        | ((unsigned)(w2 & 255) << 16)
                        | ((unsigned)w3 << 24);
            w_lds[r * 17 + c4] = (int)pw;

            v4i x4 = xv[j];
            unsigned px = (unsigned)(x4.x & 255)
                        | ((unsigned)(x4.y & 255) << 8)
                        | ((unsigned)(x4.z & 255) << 16)
                        | ((unsigned)x4.w << 24);
            x_lds[r * 17 + c4] = (int)px;
        }

        // ---- prefetch next tile into regs (in flight across barrier/compute) ----
        if (it + 1 < NT) {
            #pragma unroll
            for (int j = 0; j < 4; ++j) {
                int r = rbase + 16 * j;
                qv[j] = *(const v4i*)(qweight + (size_t)(n0 + r) * KK + (it + 1) * BK + c4 * 4);
                xv[j] = *(const v4i*)(x       + (size_t)r        * KK + (it + 1) * BK + c4 * 4);
            }
        }

        __syncthreads();

        // ---- compute: 4x mfma_i32_16x16x64_i8 per wave ----
        // B frag: col n = wv*16 + arow, k bytes = kq*16 + 0..15
        v4i bv;
        {
            int base = (wv * 16 + arow) * 17 + kq * 4;
            bv.x = w_lds[base + 0];
            bv.y = w_lds[base + 1];
            bv.z = w_lds[base + 2];
            bv.w = w_lds[base + 3];
        }
        #pragma unroll
        for (int q = 0; q < 4; ++q) {
            int base = (q * 16 + arow) * 17 + kq * 4;
            v4i av;
            av.x = x_lds[base + 0];
            av.y = x_lds[base + 1];
            av.z = x_lds[base + 2];
            av.w = x_lds[base + 3];
            acc[q] = __builtin_amdgcn_mfma_i32_16x16x64_i8(av, bv, acc[q], 0, 0, 0);
        }

        __syncthreads();
    }

    // ---- epilogue: exact int32 acc -> fp32 scale + bias ----
    // D layout: col = lane&15, row = (lane>>4)*4 + reg (dtype-independent on gfx950)
    const int n = n0 + wv * 16 + arow;
    const float s1b = s1_scales[n];
    const float bb  = bias[n];
    #pragma unroll
    for (int q = 0; q < 4; ++q) {
        #pragma unroll
        for (int r = 0; r < 4; ++r) {
            int m = q * 16 + kq * 4 + r;
            float v = (float)acc[q][r] * input_scales[m] * s1b + bb;
            out[(size_t)m * NN + n] = v;
        }
    }
}

extern "C" void kernel_launch(void* const* d_in, const int* in_sizes, int n_in,
                              void* d_out, int out_size, void* d_ws, size_t ws_size,
                              hipStream_t stream) {
    const int*   xx    = (const int*)d_in[0];    // x [64,4096]
    const float* iscal = (const float*)d_in[1];  // input_scales [64]
    // d_in[2] = input_sum (unused by this formulation)
    const int*   qw    = (const int*)d_in[3];    // qweight [14336,4096]
    const int*   s2s   = (const int*)d_in[4];    // s2_scales [32,14336]
    const int*   s2z   = (const int*)d_in[5];    // s2_zeros [32,14336]
    const float* s1    = (const float*)d_in[6];  // s1_scales [14336]
    const float* bb    = (const float*)d_in[7];  // bias [14336]
    float* outp = (float*)d_out;

    hipLaunchKernelGGL(w4a8_gemm_kernel, dim3(NN / BN), dim3(256), 0, stream,
                       xx, iscal, qw, s2s, s2z, s1, bb, outp);
}

// Round 2
// 329.349 us; speedup vs baseline: 1.0528x; 1.0528x over previous
//
#include <hip/hip_runtime.h>

// W4A8 per-group GEMM, MI355X (gfx950), K-split version.
// out[m,n] = (sum_k x_i8[m,k] * (q4[n,k]*s2[g,n] + z[g,n])) * is[m] * s1[n] + b[n]
// w_int8 = q*s2+z fits [-105,105] -> exact int8 MFMA path, dequant during LDS staging.
// K split 4-ways across blocks (896 blocks ~ 3.5/CU for latency hiding);
// int32 partials to workspace, fused scale epilogue kernel.

typedef int v4i __attribute__((ext_vector_type(4)));

#define MM 64
#define KK 4096
#define NN 14336
#define BN 64
#define BK 64
#define KS 4                  // K-split factor
#define KCH (KK / KS)         // 1024 k per block
#define NT (KCH / BK)         // 16 k-tiles per block
#define GPB (KCH / 128)       // 8 groups per block

__global__ __launch_bounds__(256, 4) void w4a8_gemm_kernel(
    const int* __restrict__ x,            // [64][4096] int8 in int32
    const int* __restrict__ qweight,      // [14336][4096] uint4 in int32
    const int* __restrict__ s2_scales,    // [32][14336]
    const int* __restrict__ s2_zeros,     // [32][14336]
    int* __restrict__ partial)            // [KS][64][14336] int32
{
    // +1 dword row pad -> 17-dword stride: ~2 lanes/bank on b128 reads (free).
    __shared__ int x_lds[64 * 17];
    __shared__ int w_lds[64 * 17];
    __shared__ int s2_lds[GPB * BN];
    __shared__ int z_lds[GPB * BN];

    const int t  = threadIdx.x;
    const int n0 = blockIdx.x * BN;
    const int ks = blockIdx.y;
    const int k0 = ks * KCH;

    // Preload this block's s2/z panels (8 g x 64 n).
    for (int i = t; i < GPB * BN; i += 256) {
        int g = i >> 6;
        int n = i & 63;
        s2_lds[i] = s2_scales[(size_t)(ks * GPB + g) * NN + n0 + n];
        z_lds[i]  = s2_zeros [(size_t)(ks * GPB + g) * NN + n0 + n];
    }

    // Staging map: thread t covers rows r = (t>>4)+16j (j=0..3), dword-quad c4 = t&15.
    // 16 lanes x 16B = 256B contiguous per row chunk.
    const int rbase = t >> 4;
    const int c4    = t & 15;

    v4i qv[4], xv[4];
    #pragma unroll
    for (int j = 0; j < 4; ++j) {
        int r = rbase + 16 * j;
        qv[j] = __builtin_nontemporal_load(
                    (const v4i*)(qweight + (size_t)(n0 + r) * KK + k0 + c4 * 4));
        xv[j] = *(const v4i*)(x + (size_t)r * KK + k0 + c4 * 4);
    }

    __syncthreads();  // s2/z panels ready (first-tile loads already in flight)

    const int lane = t & 63;
    const int wv   = t >> 6;      // wave id 0..3 -> n sub-tile
    const int arow = lane & 15;
    const int kq   = lane >> 4;   // 0..3 k-quarter

    v4i acc[4];
    #pragma unroll
    for (int q = 0; q < 4; ++q) acc[q] = (v4i){0, 0, 0, 0};

    for (int it = 0; it < NT; ++it) {
        const int g = it >> 1;  // local group (128 k = 2 tiles per group)

        // ---- dequant + pack into LDS (consumes qv/xv) ----
        #pragma unroll
        for (int j = 0; j < 4; ++j) {
            int r = rbase + 16 * j;
            int s2v = s2_lds[g * 64 + r];
            int zv  = z_lds [g * 64 + r];
            v4i q4 = qv[j];
            int w0 = q4.x * s2v + zv;
            int w1 = q4.y * s2v + zv;
            int w2 = q4.z * s2v + zv;
            int w3 = q4.w * s2v + zv;
            unsigned pw = (unsigned)(w0 & 255)
                        | ((unsigned)(w1 & 255) << 8)
                        | ((unsigned)(w2 & 255) << 16)
                        | ((unsigned)w3 << 24);
            w_lds[r * 17 + c4] = (int)pw;

            v4i x4 = xv[j];
            unsigned px = (unsigned)(x4.x & 255)
                        | ((unsigned)(x4.y & 255) << 8)
                        | ((unsigned)(x4.z & 255) << 16)
                        | ((unsigned)x4.w << 24);
            x_lds[r * 17 + c4] = (int)px;
        }

        // ---- prefetch next tile into regs (in flight across barrier/compute) ----
        if (it + 1 < NT) {
            #pragma unroll
            for (int j = 0; j < 4; ++j) {
                int r = rbase + 16 * j;
                qv[j] = __builtin_nontemporal_load(
                            (const v4i*)(qweight + (size_t)(n0 + r) * KK + k0 + (it + 1) * BK + c4 * 4));
                xv[j] = *(const v4i*)(x + (size_t)r * KK + k0 + (it + 1) * BK + c4 * 4);
            }
        }

        __syncthreads();

        // ---- compute: 4x mfma_i32_16x16x64_i8 per wave ----
        v4i bv;
        {
            int base = (wv * 16 + arow) * 17 + kq * 4;
            bv.x = w_lds[base + 0];
            bv.y = w_lds[base + 1];
            bv.z = w_lds[base + 2];
            bv.w = w_lds[base + 3];
        }
        #pragma unroll
        for (int q = 0; q < 4; ++q) {
            int base = (q * 16 + arow) * 17 + kq * 4;
            v4i av;
            av.x = x_lds[base + 0];
            av.y = x_lds[base + 1];
            av.z = x_lds[base + 2];
            av.w = x_lds[base + 3];
            acc[q] = __builtin_amdgcn_mfma_i32_16x16x64_i8(av, bv, acc[q], 0, 0, 0);
        }

        __syncthreads();
    }

    // ---- write int32 partials (no init needed: fully overwritten) ----
    // D layout: col = lane&15, row = (lane>>4)*4 + reg
    const int n = n0 + wv * 16 + arow;
    int* pbase = partial + (size_t)ks * MM * NN;
    #pragma unroll
    for (int q = 0; q < 4; ++q) {
        #pragma unroll
        for (int r = 0; r < 4; ++r) {
            int m = q * 16 + kq * 4 + r;
            pbase[(size_t)m * NN + n] = acc[q][r];
        }
    }
}

__global__ __launch_bounds__(256) void w4a8_epilogue_kernel(
    const int* __restrict__ partial,        // [KS][64][14336]
    const float* __restrict__ input_scales, // [64]
    const float* __restrict__ s1_scales,    // [14336]
    const float* __restrict__ bias,         // [14336]
    float* __restrict__ out)                // [64][14336] fp32
{
    const int idx = blockIdx.x * 256 + threadIdx.x;   // vec4 index
    const int npv = NN / 4;                            // 3584
    const int m  = idx / npv;
    const int n  = (idx - m * npv) * 4;
    const size_t base  = (size_t)m * NN + n;
    const size_t plane = (size_t)MM * NN;

    v4i a0 = __builtin_nontemporal_load((const v4i*)(partial + 0 * plane + base));
    v4i a1 = __builtin_nontemporal_load((const v4i*)(partial + 1 * plane + base));
    v4i a2 = __builtin_nontemporal_load((const v4i*)(partial + 2 * plane + base));
    v4i a3 = __builtin_nontemporal_load((const v4i*)(partial + 3 * plane + base));

    const float is = input_scales[m];
    const float4 s1 = *(const float4*)(s1_scales + n);
    const float4 bb = *(const float4*)(bias + n);

    float4 o;
    o.x = (float)(a0.x + a1.x + a2.x + a3.x) * is * s1.x + bb.x;
    o.y = (float)(a0.y + a1.y + a2.y + a3.y) * is * s1.y + bb.y;
    o.z = (float)(a0.z + a1.z + a2.z + a3.z) * is * s1.z + bb.z;
    o.w = (float)(a0.w + a1.w + a2.w + a3.w) * is * s1.w + bb.w;
    *(float4*)(out + base) = o;
}

extern "C" void kernel_launch(void* const* d_in, const int* in_sizes, int n_in,
                              void* d_out, int out_size, void* d_ws, size_t ws_size,
                              hipStream_t stream) {
    const int*   xx    = (const int*)d_in[0];    // x [64,4096]
    const float* iscal = (const float*)d_in[1];  // input_scales [64]
    // d_in[2] = input_sum (unused)
    const int*   qw    = (const int*)d_in[3];    // qweight [14336,4096]
    const int*   s2s   = (const int*)d_in[4];    // s2_scales [32,14336]
    const int*   s2z   = (const int*)d_in[5];    // s2_zeros [32,14336]
    const float* s1    = (const float*)d_in[6];  // s1_scales [14336]
    const float* bb    = (const float*)d_in[7];  // bias [14336]
    float* outp = (float*)d_out;
    int*   part = (int*)d_ws;                    // [4][64][14336] = 14.7 MB

    hipLaunchKernelGGL(w4a8_gemm_kernel, dim3(NN / BN, KS), dim3(256), 0, stream,
                       xx, qw, s2s, s2z, part);
    hipLaunchKernelGGL(w4a8_epilogue_kernel, dim3((MM * NN / 4) / 256), dim3(256), 0, stream,
                       part, iscal, s1, bb, outp);
}